// Round 5
// baseline (305.334 us; speedup 1.0000x reference)
//
#include <hip/hip_runtime.h>

// B=2048, N=64, D=256, H=16.
// out[b,n] = softmax_n( relu( ((N*u[b,n,:] - sum_n u) * item) @ W1 + b1 ) @ W2 )
// b2 dropped. y'[n,h] = (u[n,:]*item) @ W1[:,h]; z = 64*y' - sum_n y' + b1.
//
// R5: one batch per 256-thread block (2048 blocks). u staged global->LDS with
// __builtin_amdgcn_global_load_lds width=16: each inst = one contiguous 1-KB
// row segment (m13-pattern wave-contiguous requests -- fixes the scattered
// 16-line/inst pattern of r2-r4 direct loads). Per-row 16-B LDS pad (via
// per-inst base) breaks the 32-way compute-read conflict down to the b128
// 8-way floor. W1 staged once per block, xor-swizzled -> n0-broadcast,
// conflict-free. 50 KB LDS -> 3 blocks/CU = 12 waves/CU. waves_per_eu(3,3)
// caps VGPR ~168 (est ~135): no spill. NO lambdas/array-refs (r4 lesson).

static constexpr int RSTRIDE = 260;  // floats per staged row: 256 + 4 pad (1040 B; 1040 % 128 = 16 -> 4-word bank step/row)
static constexpr int PSTRIDE = 68;   // epilogue partial row stride (floats)

typedef const __attribute__((address_space(1))) unsigned int glds_g;
typedef __attribute__((address_space(3))) unsigned int glds_l;

__device__ __forceinline__ void stage16(const float* g, float* l) {
    __builtin_amdgcn_global_load_lds((glds_g*)g, (glds_l*)l, 16, 0, 0);
}

__global__ __launch_bounds__(256) __attribute__((amdgpu_waves_per_eu(3, 3)))
void attn_group_softmax(const float* __restrict__ u_g,     // [B,64,256]
                        const float* __restrict__ item_g,  // [B,256]
                        const float* __restrict__ W1,      // [256,16]
                        const float* __restrict__ b1,      // [16]
                        const float* __restrict__ W2,      // [16,1]
                        float* __restrict__ out)           // [B,64]
{
    __shared__ __align__(16) float w1s[256 * 16];      // 16 KB, xor-swizzled
    __shared__ __align__(16) float utile[32 * RSTRIDE]; // 33.3 KB: 32 staged rows (padded)

    const int tid  = threadIdx.x;
    const int w    = tid >> 6;     // wave 0..3: owns d in [64w, 64w+64)
    const int lane = tid & 63;
    const int b    = blockIdx.x;   // one batch per block

    const int q  = lane & 3;       // d-sub: lane owns d in [64w+16q, 64w+16q+16)
    const int n0 = lane >> 2;      // tile-local rows n0, n0+16

    const float* ub = u_g + (size_t)b * (64 * 256);

    // ---- stage W1 swizzled: (d, c) -> slot c ^ ((d>>4)&3) ----
    {
        const int d = tid;
        const float4* src = (const float4*)(W1 + d * 16);
        const int sw = (d >> 4) & 3;
        float* dst = w1s + d * 16;
        #pragma unroll
        for (int c = 0; c < 4; ++c)
            *(float4*)(dst + ((c ^ sw) * 4)) = src[c];
    }

    // ---- issue stage of tile 0 (rows 0..31): 8 contiguous-1KB insts per wave ----
    #pragma unroll
    for (int i = 0; i < 8; ++i) {
        const int row = 8 * w + i;  // tile-local
        stage16(ub + (size_t)row * 256 + lane * 4, utile + row * RSTRIDE + lane * 4);
    }

    // ---- item fragment for this lane's 16 d (4 float4s), from global ----
    const float4* it4 = (const float4*)(item_g + (size_t)b * 256);
    float4 itemr[4];
    #pragma unroll
    for (int j = 0; j < 4; ++j) itemr[j] = it4[16 * w + 4 * q + j];

    float acc[4][16];
    #pragma unroll
    for (int k = 0; k < 4; ++k)
        #pragma unroll
        for (int h = 0; h < 16; ++h) acc[k][h] = 0.f;

    // ---- two tiles: t=0 rows 0..31 (acc k=0,1), t=1 rows 32..63 (acc k=2,3) ----
    #pragma unroll
    for (int t = 0; t < 2; ++t) {
        __syncthreads();   // staged tile t visible (drains global_load_lds + prior reads)

        #pragma unroll
        for (int j = 0; j < 4; ++j) {
            const float* urow0 = utile + n0 * RSTRIDE + (16 * w + 4 * q + j) * 4;
            const float* urow1 = urow0 + 16 * RSTRIDE;
            const float4 u0 = *(const float4*)urow0;
            const float4 u1 = *(const float4*)urow1;
            float s0[4], s1[4];
            s0[0] = u0.x * itemr[j].x;  s1[0] = u1.x * itemr[j].x;
            s0[1] = u0.y * itemr[j].y;  s1[1] = u1.y * itemr[j].y;
            s0[2] = u0.z * itemr[j].z;  s1[2] = u1.z * itemr[j].z;
            s0[3] = u0.w * itemr[j].w;  s1[3] = u1.w * itemr[j].w;

            #pragma unroll
            for (int dd = 0; dd < 4; ++dd) {
                const int d = 64 * w + 16 * q + 4 * j + dd;
                const float* wb = w1s + d * 16;   // (d>>4)&3 == q here
                const float4 wv0 = *(const float4*)(wb + ((0 ^ q) * 4));
                const float4 wv1 = *(const float4*)(wb + ((1 ^ q) * 4));
                const float4 wv2 = *(const float4*)(wb + ((2 ^ q) * 4));
                const float4 wv3 = *(const float4*)(wb + ((3 ^ q) * 4));
                const float a = s0[dd], c2 = s1[dd];
                const int k0 = 2 * t, k1 = 2 * t + 1;
                acc[k0][ 0] = fmaf(a, wv0.x, acc[k0][ 0]);  acc[k1][ 0] = fmaf(c2, wv0.x, acc[k1][ 0]);
                acc[k0][ 1] = fmaf(a, wv0.y, acc[k0][ 1]);  acc[k1][ 1] = fmaf(c2, wv0.y, acc[k1][ 1]);
                acc[k0][ 2] = fmaf(a, wv0.z, acc[k0][ 2]);  acc[k1][ 2] = fmaf(c2, wv0.z, acc[k1][ 2]);
                acc[k0][ 3] = fmaf(a, wv0.w, acc[k0][ 3]);  acc[k1][ 3] = fmaf(c2, wv0.w, acc[k1][ 3]);
                acc[k0][ 4] = fmaf(a, wv1.x, acc[k0][ 4]);  acc[k1][ 4] = fmaf(c2, wv1.x, acc[k1][ 4]);
                acc[k0][ 5] = fmaf(a, wv1.y, acc[k0][ 5]);  acc[k1][ 5] = fmaf(c2, wv1.y, acc[k1][ 5]);
                acc[k0][ 6] = fmaf(a, wv1.z, acc[k0][ 6]);  acc[k1][ 6] = fmaf(c2, wv1.z, acc[k1][ 6]);
                acc[k0][ 7] = fmaf(a, wv1.w, acc[k0][ 7]);  acc[k1][ 7] = fmaf(c2, wv1.w, acc[k1][ 7]);
                acc[k0][ 8] = fmaf(a, wv2.x, acc[k0][ 8]);  acc[k1][ 8] = fmaf(c2, wv2.x, acc[k1][ 8]);
                acc[k0][ 9] = fmaf(a, wv2.y, acc[k0][ 9]);  acc[k1][ 9] = fmaf(c2, wv2.y, acc[k1][ 9]);
                acc[k0][10] = fmaf(a, wv2.z, acc[k0][10]);  acc[k1][10] = fmaf(c2, wv2.z, acc[k1][10]);
                acc[k0][11] = fmaf(a, wv2.w, acc[k0][11]);  acc[k1][11] = fmaf(c2, wv2.w, acc[k1][11]);
                acc[k0][12] = fmaf(a, wv3.x, acc[k0][12]);  acc[k1][12] = fmaf(c2, wv3.x, acc[k1][12]);
                acc[k0][13] = fmaf(a, wv3.y, acc[k0][13]);  acc[k1][13] = fmaf(c2, wv3.y, acc[k1][13]);
                acc[k0][14] = fmaf(a, wv3.z, acc[k0][14]);  acc[k1][14] = fmaf(c2, wv3.z, acc[k1][14]);
                acc[k0][15] = fmaf(a, wv3.w, acc[k0][15]);  acc[k1][15] = fmaf(c2, wv3.w, acc[k1][15]);
            }
        }

        __syncthreads();   // tile t consumed
        if (t == 0) {
            // stage tile 1 (rows 32..63) into the same buffer
            #pragma unroll
            for (int i = 0; i < 8; ++i) {
                const int row = 8 * w + i;
                stage16(ub + (size_t)(32 + row) * 256 + lane * 4,
                        utile + row * RSTRIDE + lane * 4);
            }
        }
    }

    // ---- reduce q-partials in-wave (xor 1,2): full y' per (row, h) ----
    #pragma unroll
    for (int k = 0; k < 4; ++k)
        #pragma unroll
        for (int h = 0; h < 16; ++h) {
            float v = acc[k][h];
            v += __shfl_xor(v, 1, 64);
            v += __shfl_xor(v, 2, 64);
            acc[k][h] = v;   // wave-w partial (its 64-d range), q-replicated
        }

    // ---- write per-wave partials to LDS (reuse utile; padded stride) ----
    if (q == 0) {
        float* pb = utile + (w * 16 + n0) * PSTRIDE;
        #pragma unroll
        for (int k = 0; k < 4; ++k)
            #pragma unroll
            for (int c = 0; c < 4; ++c)
                *(float4*)(pb + k * 16 + c * 4) =
                    make_float4(acc[k][4*c+0], acc[k][4*c+1], acc[k][4*c+2], acc[k][4*c+3]);
    }
    __syncthreads();

    if (w != 0) return;   // wave 0 finishes the block

    // ---- sum the 4 wave-partials: v[k][h] = full y'[n0+16k][h] ----
    float v[4][16];
    #pragma unroll
    for (int k = 0; k < 4; ++k)
        #pragma unroll
        for (int c = 0; c < 4; ++c) {
            float4 s = make_float4(0.f, 0.f, 0.f, 0.f);
            #pragma unroll
            for (int wv = 0; wv < 4; ++wv) {
                const float4 p = *(const float4*)(utile + (wv * 16 + n0) * PSTRIDE + k * 16 + c * 4);
                s.x += p.x; s.y += p.y; s.z += p.z; s.w += p.w;
            }
            v[k][4*c+0] = s.x; v[k][4*c+1] = s.y; v[k][4*c+2] = s.z; v[k][4*c+3] = s.w;
        }

    // ---- tt[h] = sum over all 64 members ----
    float tt[16];
    #pragma unroll
    for (int h = 0; h < 16; ++h) {
        float s = v[0][h] + v[1][h] + v[2][h] + v[3][h];
        #pragma unroll
        for (int off = 4; off <= 32; off <<= 1) s += __shfl_xor(s, off, 64);
        tt[h] = s;
    }

    // ---- b1 / W2 ----
    float b1c[16], w2c[16];
    {
        const float4* b4 = (const float4*)b1;
        const float4* w4 = (const float4*)W2;
        #pragma unroll
        for (int c = 0; c < 4; ++c) {
            const float4 t1 = b4[c], t2 = w4[c];
            b1c[4*c+0] = t1.x; b1c[4*c+1] = t1.y; b1c[4*c+2] = t1.z; b1c[4*c+3] = t1.w;
            w2c[4*c+0] = t2.x; w2c[4*c+1] = t2.y; w2c[4*c+2] = t2.z; w2c[4*c+3] = t2.w;
        }
    }

    // ---- logits: z = 64*y' - tt + b1, relu, dot W2 (v is full: no q-reduce) ----
    float p[4];
    #pragma unroll
    for (int k = 0; k < 4; ++k) {
        float sum = 0.f;
        #pragma unroll
        for (int h = 0; h < 16; ++h) {
            float z = fmaf(64.f, v[k][h], b1c[h] - tt[h]);
            z = fmaxf(z, 0.f);
            sum = fmaf(z, w2c[h], sum);
        }
        p[k] = sum;
    }

    // ---- softmax over 64 members (16 n0-lanes x 4 rows, q-replicated) ----
    float m = fmaxf(fmaxf(p[0], p[1]), fmaxf(p[2], p[3]));
    #pragma unroll
    for (int off = 4; off <= 32; off <<= 1) m = fmaxf(m, __shfl_xor(m, off, 64));
    const float e0 = __expf(p[0] - m);
    const float e1 = __expf(p[1] - m);
    const float e2 = __expf(p[2] - m);
    const float e3 = __expf(p[3] - m);
    float sden = e0 + e1 + e2 + e3;
    #pragma unroll
    for (int off = 4; off <= 32; off <<= 1) sden += __shfl_xor(sden, off, 64);
    const float inv = 1.0f / sden;

    if (q == 0) {
        float* ob = out + (size_t)b * 64 + n0;
        ob[0]  = e0 * inv;
        ob[16] = e1 * inv;
        ob[32] = e2 * inv;
        ob[48] = e3 * inv;
    }
}

extern "C" void kernel_launch(void* const* d_in, const int* in_sizes, int n_in,
                              void* d_out, int out_size, void* d_ws, size_t ws_size,
                              hipStream_t stream) {
    const float* u    = (const float*)d_in[0];  // members_embeds [2048,64,256]
    const float* item = (const float*)d_in[1];  // item_embeds   [2048,256]
    const float* W1   = (const float*)d_in[2];  // [256,16]
    const float* b1   = (const float*)d_in[3];  // [16]
    const float* W2   = (const float*)d_in[4];  // [16,1]
    // d_in[5] = b2: dropped (softmax shift-invariant)
    (void)in_sizes; (void)n_in; (void)out_size; (void)d_ws; (void)ws_size;

    attn_group_softmax<<<2048, 256, 0, stream>>>(u, item, W1, b1, W2, (float*)d_out);
}